// Round 2
// baseline (402.872 us; speedup 1.0000x reference)
//
#include <hip/hip_runtime.h>
#include <hip/hip_bf16.h>

namespace {

constexpr int E  = 64;
constexpr int C  = 64;
constexpr int D  = 1024;
constexpr int DF = 2048;
constexpr int BN = 128;   // N-tile per block

using u16    = unsigned short;
using f32x4  = __attribute__((ext_vector_type(4))) float;
using short8 = __attribute__((ext_vector_type(8))) short;

__device__ __forceinline__ u16 f2bf(float f) {
  union { float f; unsigned u; } v;
  v.f = f;
  unsigned u = v.u;
  return (u16)((u + 0x7fffu + ((u >> 16) & 1u)) >> 16);  // RNE
}

__device__ __forceinline__ short8 cvt8(const f32x4& lo, const f32x4& hi) {
  short8 r;
#pragma unroll
  for (int i = 0; i < 4; ++i) {
    r[i]     = (short)f2bf(lo[i]);
    r[4 + i] = (short)f2bf(hi[i]);
  }
  return r;
}

// ---------------- Stage 1: H = silu(X*Wg^T) * (X*Wu^T), bf16 out -----------
// Zero LDS, zero barriers. Fragments loaded direct from global in MFMA layout.
__global__ __launch_bounds__(256, 2) void ffn_stage1(
    const float* __restrict__ X, const float* __restrict__ Wg,
    const float* __restrict__ Wu, u16* __restrict__ H) {
  // bijective expert-major XCD swizzle: all 16 DF-tiles of expert e on XCD e%8
  const int b   = blockIdx.x;          // 0..1023
  const int xcd = b & 7;
  const int j   = b >> 3;              // 0..127
  const int e   = xcd + 8 * (j >> 4);  // expert 0..63
  const int n0  = (j & 15) * BN;       // DF tile origin

  const int tid  = threadIdx.x;
  const int lane = tid & 63;
  const int wv   = tid >> 6;
  const int rl   = lane & 15;          // fragment row within 16
  const int kq   = (lane >> 4) * 8;    // k sub-offset within 32

  // per-lane fragment base pointers (k advances by 32 floats per step)
  const float* xb = X  + ((size_t)(e * C) + rl) * D + kq;
  const float* gb = Wg + ((size_t)e * DF + n0 + wv * 32 + rl) * D + kq;
  const float* ub = Wu + ((size_t)e * DF + n0 + wv * 32 + rl) * D + kq;

  const f32x4 zero = {0.f, 0.f, 0.f, 0.f};
  f32x4 accg[4][2], accu[4][2];
#pragma unroll
  for (int mf = 0; mf < 4; ++mf)
#pragma unroll
    for (int nf = 0; nf < 2; ++nf) { accg[mf][nf] = zero; accu[mf][nf] = zero; }

  f32x4 A[8], G0[4], U0[4], G1[4], U1[4];

  auto LOADA = [&](int kt) {
#pragma unroll
    for (int mf = 0; mf < 4; ++mf) {
      const f32x4* p = reinterpret_cast<const f32x4*>(xb + (size_t)mf * 16 * D + kt * 32);
      A[2 * mf] = p[0]; A[2 * mf + 1] = p[1];
    }
  };
  auto LOADB = [&](f32x4 (&G)[4], f32x4 (&U)[4], int kt) {
#pragma unroll
    for (int nf = 0; nf < 2; ++nf) {
      const f32x4* g = reinterpret_cast<const f32x4*>(gb + (size_t)nf * 16 * D + kt * 32);
      G[2 * nf] = g[0]; G[2 * nf + 1] = g[1];
      const f32x4* u = reinterpret_cast<const f32x4*>(ub + (size_t)nf * 16 * D + kt * 32);
      U[2 * nf] = u[0]; U[2 * nf + 1] = u[1];
    }
  };
  auto COMPUTE = [&](f32x4 (&G)[4], f32x4 (&U)[4]) {
    short8 a[4], g[2], u[2];
#pragma unroll
    for (int mf = 0; mf < 4; ++mf) a[mf] = cvt8(A[2 * mf], A[2 * mf + 1]);
#pragma unroll
    for (int nf = 0; nf < 2; ++nf) {
      g[nf] = cvt8(G[2 * nf], G[2 * nf + 1]);
      u[nf] = cvt8(U[2 * nf], U[2 * nf + 1]);
    }
#pragma unroll
    for (int mf = 0; mf < 4; ++mf)
#pragma unroll
      for (int nf = 0; nf < 2; ++nf) {
        accg[mf][nf] = __builtin_amdgcn_mfma_f32_16x16x32_bf16(a[mf], g[nf], accg[mf][nf], 0, 0, 0);
        accu[mf][nf] = __builtin_amdgcn_mfma_f32_16x16x32_bf16(a[mf], u[nf], accu[mf][nf], 0, 0, 0);
      }
  };

  constexpr int NK = D / 32;  // 32
  LOADB(G0, U0, 0);
  for (int kt = 0; kt < NK; kt += 2) {
    LOADB(G1, U1, kt + 1);     // prefetch next B stream (HBM)
    LOADA(kt);                 // A is L2-hot (X tile shared by 16 blocks)
    COMPUTE(G0, U0);
    if (kt + 2 < NK) LOADB(G0, U0, kt + 2);
    LOADA(kt + 1);
    COMPUTE(G1, U1);
  }

  // epilogue: silu(g)*u -> bf16. C/D layout: col=lane&15, row=(lane>>4)*4+reg
#pragma unroll
  for (int mf = 0; mf < 4; ++mf)
#pragma unroll
    for (int nf = 0; nf < 2; ++nf)
#pragma unroll
      for (int r = 0; r < 4; ++r) {
        float g = accg[mf][nf][r];
        float u = accu[mf][nf][r];
        float h = (g / (1.f + __expf(-g))) * u;
        int c = mf * 16 + (lane >> 4) * 4 + r;
        int f = n0 + wv * 32 + nf * 16 + rl;
        H[((size_t)(e * C) + c) * DF + f] = f2bf(h);
      }
}

// ---------------- Stage 2: out = H * Wd^T (fp32 out) -----------------------
__global__ __launch_bounds__(256, 2) void ffn_stage2(
    const u16* __restrict__ H, const float* __restrict__ Wd,
    float* __restrict__ out) {
  const int b   = blockIdx.x;          // 0..511
  const int xcd = b & 7;
  const int j   = b >> 3;              // 0..63
  const int e   = xcd + 8 * (j >> 3);  // expert: same XCD that wrote H[e]
  const int n0  = (j & 7) * BN;

  const int tid  = threadIdx.x;
  const int lane = tid & 63;
  const int wv   = tid >> 6;
  const int rl   = lane & 15;
  const int kq   = (lane >> 4) * 8;

  const u16*   ab = H  + ((size_t)(e * C) + rl) * DF + kq;
  const float* bb = Wd + ((size_t)e * D + n0 + wv * 32 + rl) * DF + kq;

  const f32x4 zero = {0.f, 0.f, 0.f, 0.f};
  f32x4 acc[4][2];
#pragma unroll
  for (int mf = 0; mf < 4; ++mf)
#pragma unroll
    for (int nf = 0; nf < 2; ++nf) acc[mf][nf] = zero;

  short8 A[4];
  f32x4  B0[4], B1[4];

  auto LOADA = [&](int kt) {
#pragma unroll
    for (int mf = 0; mf < 4; ++mf)
      A[mf] = *reinterpret_cast<const short8*>(ab + (size_t)mf * 16 * DF + kt * 32);
  };
  auto LOADB = [&](f32x4 (&B)[4], int kt) {
#pragma unroll
    for (int nf = 0; nf < 2; ++nf) {
      const f32x4* p = reinterpret_cast<const f32x4*>(bb + (size_t)nf * 16 * DF + kt * 32);
      B[2 * nf] = p[0]; B[2 * nf + 1] = p[1];
    }
  };
  auto COMPUTE = [&](f32x4 (&B)[4]) {
    short8 bfr[2];
#pragma unroll
    for (int nf = 0; nf < 2; ++nf) bfr[nf] = cvt8(B[2 * nf], B[2 * nf + 1]);
#pragma unroll
    for (int mf = 0; mf < 4; ++mf)
#pragma unroll
      for (int nf = 0; nf < 2; ++nf)
        acc[mf][nf] = __builtin_amdgcn_mfma_f32_16x16x32_bf16(A[mf], bfr[nf], acc[mf][nf], 0, 0, 0);
  };

  constexpr int NK = DF / 32;  // 64
  LOADB(B0, 0);
  for (int kt = 0; kt < NK; kt += 2) {
    LOADB(B1, kt + 1);
    LOADA(kt);
    COMPUTE(B0);
    if (kt + 2 < NK) LOADB(B0, kt + 2);
    LOADA(kt + 1);
    COMPUTE(B1);
  }

#pragma unroll
  for (int mf = 0; mf < 4; ++mf)
#pragma unroll
    for (int nf = 0; nf < 2; ++nf)
#pragma unroll
      for (int r = 0; r < 4; ++r) {
        int c = mf * 16 + (lane >> 4) * 4 + r;
        int d = n0 + wv * 32 + nf * 16 + rl;
        out[((size_t)(e * C) + c) * D + d] = acc[mf][nf][r];
      }
}

}  // namespace

extern "C" void kernel_launch(void* const* d_in, const int* in_sizes, int n_in,
                              void* d_out, int out_size, void* d_ws, size_t ws_size,
                              hipStream_t stream) {
  const float* X  = (const float*)d_in[0];
  const float* Wg = (const float*)d_in[1];
  const float* Wu = (const float*)d_in[2];
  const float* Wd = (const float*)d_in[3];
  float* out = (float*)d_out;
  u16* H = (u16*)d_ws;  // E*C*DF bf16 = 16.8 MB scratch

  ffn_stage1<<<dim3(E * (DF / BN)), dim3(256), 0, stream>>>(X, Wg, Wu, H);
  ffn_stage2<<<dim3(E * (D / BN)), dim3(256), 0, stream>>>(H, Wd, out);
}

// Round 3
// 351.359 us; speedup vs baseline: 1.1466x; 1.1466x over previous
//
#include <hip/hip_runtime.h>
#include <hip/hip_bf16.h>

namespace {

constexpr int E  = 64;
constexpr int C  = 64;
constexpr int D  = 1024;
constexpr int DF = 2048;
constexpr int BN = 128;   // N rows per block tile
constexpr int BK = 32;    // K per step (32 f32 = 128 B rows in LDS)

using u16    = unsigned short;
using f32x4  = __attribute__((ext_vector_type(4))) float;
using short8 = __attribute__((ext_vector_type(8))) short;

__device__ __forceinline__ u16 f2bf(float f) {
  union { float f; unsigned u; } v;
  v.f = f;
  unsigned u = v.u;
  return (u16)((u + 0x7fffu + ((u >> 16) & 1u)) >> 16);  // RNE
}

__device__ __forceinline__ short8 cvt8(const f32x4& lo, const f32x4& hi) {
  short8 r;
#pragma unroll
  for (int i = 0; i < 4; ++i) {
    r[i]     = (short)f2bf(lo[i]);
    r[4 + i] = (short)f2bf(hi[i]);
  }
  return r;
}

// async 16B global -> LDS (linear dest: wave-uniform base + lane*16)
__device__ __forceinline__ void gl_lds16(const void* g, void* l) {
  __builtin_amdgcn_global_load_lds(
      (const __attribute__((address_space(1))) unsigned*)g,
      (__attribute__((address_space(3))) unsigned*)l, 16, 0, 0);
}

// read one bf16 fragment (8 f32 -> short8) from a 128B-row fp32 LDS region,
// XOR-swizzled: granule ^ (row & 7)
__device__ __forceinline__ short8 rd_frag_f32(const char* region, int r, int q) {
  const int s  = (r & 7) << 4;
  const int b0 = r * 128 + ((q * 32) ^ s);
  const int b1 = r * 128 + ((q * 32 + 16) ^ s);
  f32x4 lo = *reinterpret_cast<const f32x4*>(region + b0);
  f32x4 hi = *reinterpret_cast<const f32x4*>(region + b1);
  return cvt8(lo, hi);
}

// ---------------- Stage 1: H = silu(X*Wg^T) * (X*Wu^T), bf16 out -----------
__global__ __launch_bounds__(256, 2) void ffn_stage1(
    const float* __restrict__ X, const float* __restrict__ Wg,
    const float* __restrict__ Wu, u16* __restrict__ H) {
  const int b   = blockIdx.x;          // 0..1023
  const int xcd = b & 7;
  const int j   = b >> 3;
  const int e   = xcd + 8 * (j >> 4);  // all 16 tiles of expert e on one XCD
  const int n0  = (j & 15) * BN;

  const int tid  = threadIdx.x;
  const int lane = tid & 63;
  const int wv   = tid >> 6;
  const int rl   = lane & 15;
  const int q    = lane >> 4;
  const int kq   = q * 8;

  __shared__ __align__(16) char lds[2][32768];  // [Wg 16KB][Wu 16KB] x dbuf
  constexpr int OU = 16384;

  const float* gbase = Wg + ((size_t)e * DF + n0) * D;
  const float* ubase = Wu + ((size_t)e * DF + n0) * D;
  const float* xb    = X + ((size_t)(e * C) + rl) * D + kq;

  // async stage of one K-tile: 8 x global_load_lds per thread,
  // global source pre-swizzled so linear LDS = swizzled layout (rule #21)
  auto STAGE = [&](int buf, int kt) {
    char* lb = lds[buf];
#pragma unroll
    for (int i = 0; i < 4; ++i) {
      const int o   = tid + i * 256;      // granule index (16B units)
      const int row = o >> 3;
      const int gc  = (o & 7) ^ (row & 7);
      const size_t goff = (size_t)row * D + (size_t)kt * BK + gc * 4;
      gl_lds16(gbase + goff, lb + o * 16);
      gl_lds16(ubase + goff, lb + OU + o * 16);
    }
  };

  const f32x4 zero = {0.f, 0.f, 0.f, 0.f};
  f32x4 accg[4][2], accu[4][2];
#pragma unroll
  for (int mf = 0; mf < 4; ++mf)
#pragma unroll
    for (int nf = 0; nf < 2; ++nf) { accg[mf][nf] = zero; accu[mf][nf] = zero; }

  STAGE(0, 0);
  __syncthreads();

  constexpr int NK = D / BK;  // 32
  int cur = 0;
  f32x4 Ar[8];

  for (int kt = 0; kt < NK; ++kt) {
    // A (X) direct from global (L2-hot) — issued BEFORE the stage so its
    // wait is a counted vmcnt, not a drain of the prefetch.
#pragma unroll
    for (int mf = 0; mf < 4; ++mf) {
      const f32x4* p = reinterpret_cast<const f32x4*>(xb + (size_t)mf * 16 * D + (size_t)kt * BK);
      Ar[2 * mf] = p[0]; Ar[2 * mf + 1] = p[1];
    }
    if (kt + 1 < NK) STAGE(cur ^ 1, kt + 1);

    const char* lb = lds[cur];
    short8 g[2], u[2];
#pragma unroll
    for (int nf = 0; nf < 2; ++nf) {
      const int r = wv * 32 + nf * 16 + rl;
      g[nf] = rd_frag_f32(lb, r, q);
      u[nf] = rd_frag_f32(lb + OU, r, q);
    }
    short8 a[4];
#pragma unroll
    for (int mf = 0; mf < 4; ++mf) a[mf] = cvt8(Ar[2 * mf], Ar[2 * mf + 1]);

#pragma unroll
    for (int mf = 0; mf < 4; ++mf)
#pragma unroll
      for (int nf = 0; nf < 2; ++nf) {
        accg[mf][nf] = __builtin_amdgcn_mfma_f32_16x16x32_bf16(a[mf], g[nf], accg[mf][nf], 0, 0, 0);
        accu[mf][nf] = __builtin_amdgcn_mfma_f32_16x16x32_bf16(a[mf], u[nf], accu[mf][nf], 0, 0, 0);
      }
    __syncthreads();  // drains this step's STAGE (vmcnt 0) + lgkm
    cur ^= 1;
  }

  // epilogue: silu(g)*u -> bf16. C/D layout: col=lane&15, row=(lane>>4)*4+reg
#pragma unroll
  for (int mf = 0; mf < 4; ++mf)
#pragma unroll
    for (int nf = 0; nf < 2; ++nf)
#pragma unroll
      for (int r = 0; r < 4; ++r) {
        float gv = accg[mf][nf][r];
        float uv = accu[mf][nf][r];
        float h  = (gv / (1.f + __expf(-gv))) * uv;
        int c = mf * 16 + (lane >> 4) * 4 + r;
        int f = n0 + wv * 32 + nf * 16 + rl;
        H[((size_t)(e * C) + c) * DF + f] = f2bf(h);
      }
}

// ---------------- Stage 2: out = H * Wd^T (fp32 out) -----------------------
__global__ __launch_bounds__(256, 4) void ffn_stage2(
    const u16* __restrict__ H, const float* __restrict__ Wd,
    float* __restrict__ out) {
  const int b   = blockIdx.x;          // 0..511
  const int xcd = b & 7;
  const int j   = b >> 3;
  const int e   = xcd + 8 * (j >> 3);  // same XCD that produced H[e]
  const int n0  = (j & 7) * BN;

  const int tid  = threadIdx.x;
  const int lane = tid & 63;
  const int wv   = tid >> 6;
  const int rl   = lane & 15;
  const int q    = lane >> 4;

  __shared__ __align__(16) char lds[2][20480];  // [H 4KB][Wd 16KB] x dbuf
  constexpr int OW = 4096;

  const u16*   hbase = H + (size_t)(e * C) * DF;
  const float* wbase = Wd + ((size_t)e * D + n0) * DF;

  auto STAGE = [&](int buf, int kt) {
    char* lb = lds[buf];
    {  // H tile: 64 rows x 32 bf16 (64B rows, 4 granules), swz c ^ ((row>>1)&3)
      const int row = tid >> 2;
      const int gc  = (tid & 3) ^ ((row >> 1) & 3);
      gl_lds16(hbase + (size_t)row * DF + (size_t)kt * BK + gc * 8, lb + tid * 16);
    }
#pragma unroll
    for (int i = 0; i < 4; ++i) {  // Wd tile: 128 rows x 32 f32, swz c ^ (row&7)
      const int o   = tid + i * 256;
      const int row = o >> 3;
      const int gc  = (o & 7) ^ (row & 7);
      gl_lds16(wbase + (size_t)row * DF + (size_t)kt * BK + gc * 4, lb + OW + o * 16);
    }
  };

  const f32x4 zero = {0.f, 0.f, 0.f, 0.f};
  f32x4 acc[4][2];
#pragma unroll
  for (int mf = 0; mf < 4; ++mf)
#pragma unroll
    for (int nf = 0; nf < 2; ++nf) acc[mf][nf] = zero;

  STAGE(0, 0);
  __syncthreads();

  constexpr int NK = DF / BK;  // 64
  int cur = 0;

  for (int kt = 0; kt < NK; ++kt) {
    if (kt + 1 < NK) STAGE(cur ^ 1, kt + 1);

    const char* lb = lds[cur];
    short8 a[4], bfr[2];
#pragma unroll
    for (int mf = 0; mf < 4; ++mf) {  // H frags: bf16 direct, swizzled read
      const int r  = mf * 16 + rl;
      const int gp = q ^ ((r >> 1) & 3);
      a[mf] = *reinterpret_cast<const short8*>(lb + r * 64 + gp * 16);
    }
#pragma unroll
    for (int nf = 0; nf < 2; ++nf) {
      const int r = wv * 32 + nf * 16 + rl;
      bfr[nf] = rd_frag_f32(lb + OW, r, q);
    }
#pragma unroll
    for (int mf = 0; mf < 4; ++mf)
#pragma unroll
      for (int nf = 0; nf < 2; ++nf)
        acc[mf][nf] = __builtin_amdgcn_mfma_f32_16x16x32_bf16(a[mf], bfr[nf], acc[mf][nf], 0, 0, 0);
    __syncthreads();
    cur ^= 1;
  }

#pragma unroll
  for (int mf = 0; mf < 4; ++mf)
#pragma unroll
    for (int nf = 0; nf < 2; ++nf)
#pragma unroll
      for (int r = 0; r < 4; ++r) {
        int c = mf * 16 + (lane >> 4) * 4 + r;
        int d = n0 + wv * 32 + nf * 16 + rl;
        out[((size_t)(e * C) + c) * D + d] = acc[mf][nf][r];
      }
}

}  // namespace

extern "C" void kernel_launch(void* const* d_in, const int* in_sizes, int n_in,
                              void* d_out, int out_size, void* d_ws, size_t ws_size,
                              hipStream_t stream) {
  const float* X  = (const float*)d_in[0];
  const float* Wg = (const float*)d_in[1];
  const float* Wu = (const float*)d_in[2];
  const float* Wd = (const float*)d_in[3];
  float* out = (float*)d_out;
  u16* H = (u16*)d_ws;  // E*C*DF bf16 = 16.8 MB scratch

  ffn_stage1<<<dim3(E * (DF / BN)), dim3(256), 0, stream>>>(X, Wg, Wu, H);
  ffn_stage2<<<dim3(E * (D / BN)), dim3(256), 0, stream>>>(H, Wd, out);
}

// Round 4
// 304.423 us; speedup vs baseline: 1.3234x; 1.1542x over previous
//
#include <hip/hip_runtime.h>
#include <hip/hip_bf16.h>

namespace {

constexpr int E  = 64;
constexpr int C  = 64;
constexpr int D  = 1024;
constexpr int DF = 2048;
constexpr int BN = 128;   // N rows per block tile
constexpr int BK = 32;    // K per step (32 f32 = 128 B rows in LDS)

using u16    = unsigned short;
using f32x4  = __attribute__((ext_vector_type(4))) float;
using short8 = __attribute__((ext_vector_type(8))) short;

__device__ __forceinline__ u16 f2bf(float f) {
  union { __hip_bfloat16 h; u16 u; } v;
  v.h = __float2bfloat16(f);  // RNE; compiler emits HW cvt (m240)
  return v.u;
}

__device__ __forceinline__ short8 cvt8(const f32x4& lo, const f32x4& hi) {
  short8 r;
#pragma unroll
  for (int i = 0; i < 4; ++i) {
    r[i]     = (short)f2bf(lo[i]);
    r[4 + i] = (short)f2bf(hi[i]);
  }
  return r;
}

// async 16B global -> LDS (linear dest: wave-uniform base + lane*16)
__device__ __forceinline__ void gl_lds16(const void* g, void* l) {
  __builtin_amdgcn_global_load_lds(
      (const __attribute__((address_space(1))) unsigned*)g,
      (__attribute__((address_space(3))) unsigned*)l, 16, 0, 0);
}

// read one bf16 fragment (8 f32 -> short8) from a 128B-row fp32 LDS region,
// XOR-swizzled: 16B-granule ^ (row & 7)  (matches the pre-swizzled source)
__device__ __forceinline__ short8 rd_frag_f32(const char* region, int r, int q) {
  const int s  = (r & 7) << 4;
  const int b0 = r * 128 + ((q * 32) ^ s);
  const int b1 = r * 128 + ((q * 32 + 16) ^ s);
  f32x4 lo = *reinterpret_cast<const f32x4*>(region + b0);
  f32x4 hi = *reinterpret_cast<const f32x4*>(region + b1);
  return cvt8(lo, hi);
}

// ---------------- Stage 1: H = silu(X*Wg^T) * (X*Wu^T), bf16 out -----------
__global__ __launch_bounds__(256, 2) void ffn_stage1(
    const float* __restrict__ X, const float* __restrict__ Wg,
    const float* __restrict__ Wu, u16* __restrict__ H) {
  const int b   = blockIdx.x;          // 0..1023
  const int xcd = b & 7;
  const int j   = b >> 3;
  const int e   = xcd + 8 * (j >> 4);  // all 16 tiles of expert e on one XCD
  const int n0  = (j & 15) * BN;

  const int tid  = threadIdx.x;
  const int lane = tid & 63;
  const int wv   = tid >> 6;
  const int rl   = lane & 15;
  const int q    = lane >> 4;

  // per buffer: X 8KB | Wg 16KB | Wu 16KB = 40KB; x2 = 80KB -> 2 blocks/CU
  __shared__ __align__(16) char lds[2][40960];
  constexpr int OX = 0, OG = 8192, OU = 24576;

  const float* xbase = X  + (size_t)(e * C) * D;
  const float* gbase = Wg + ((size_t)e * DF + n0) * D;
  const float* ubase = Wu + ((size_t)e * DF + n0) * D;

  // one K-tile: exactly 10 global_load_lds per wave (vmcnt bookkeeping!)
  auto STAGE = [&](char* lb, int kt) {
#pragma unroll
    for (int i = 0; i < 2; ++i) {  // X: 64 rows x 128B
      const int o   = tid + i * 256;
      const int row = o >> 3;
      const int gc  = (o & 7) ^ (row & 7);
      gl_lds16(xbase + (size_t)row * D + (size_t)kt * BK + gc * 4, lb + OX + o * 16);
    }
#pragma unroll
    for (int i = 0; i < 4; ++i) {  // Wg/Wu: 128 rows x 128B each
      const int o   = tid + i * 256;
      const int row = o >> 3;
      const int gc  = (o & 7) ^ (row & 7);
      const size_t goff = (size_t)row * D + (size_t)kt * BK + gc * 4;
      gl_lds16(gbase + goff, lb + OG + o * 16);
      gl_lds16(ubase + goff, lb + OU + o * 16);
    }
  };

  const f32x4 zero = {0.f, 0.f, 0.f, 0.f};
  f32x4 accg[4][2], accu[4][2];
#pragma unroll
  for (int mf = 0; mf < 4; ++mf)
#pragma unroll
    for (int nf = 0; nf < 2; ++nf) { accg[mf][nf] = zero; accu[mf][nf] = zero; }

  auto COMPUTE = [&](const char* lb) {
    short8 a[4], g[2], u[2];
#pragma unroll
    for (int mf = 0; mf < 4; ++mf)
      a[mf] = rd_frag_f32(lb + OX, mf * 16 + rl, q);
#pragma unroll
    for (int nf = 0; nf < 2; ++nf) {
      const int r = wv * 32 + nf * 16 + rl;
      g[nf] = rd_frag_f32(lb + OG, r, q);
      u[nf] = rd_frag_f32(lb + OU, r, q);
    }
#pragma unroll
    for (int mf = 0; mf < 4; ++mf)
#pragma unroll
      for (int nf = 0; nf < 2; ++nf) {
        accg[mf][nf] = __builtin_amdgcn_mfma_f32_16x16x32_bf16(a[mf], g[nf], accg[mf][nf], 0, 0, 0);
        accu[mf][nf] = __builtin_amdgcn_mfma_f32_16x16x32_bf16(a[mf], u[nf], accu[mf][nf], 0, 0, 0);
      }
  };

  constexpr int NK = D / BK;  // 32
  STAGE(lds[0], 0);
  STAGE(lds[1], 1);           // 20 outstanding

  for (int kt = 0; kt < NK - 1; ++kt) {
    // tile kt resident when only tile kt+1's 10 loads remain outstanding
    asm volatile("s_waitcnt vmcnt(10)" ::: "memory");
    __builtin_amdgcn_s_barrier();
    __builtin_amdgcn_sched_barrier(0);
    COMPUTE(lds[kt & 1]);
    __builtin_amdgcn_sched_barrier(0);
    __builtin_amdgcn_s_barrier();            // all waves done reading buf kt&1
    if (kt + 2 < NK) STAGE(lds[kt & 1], kt + 2);
  }
  asm volatile("s_waitcnt vmcnt(0)" ::: "memory");
  __builtin_amdgcn_s_barrier();
  __builtin_amdgcn_sched_barrier(0);
  COMPUTE(lds[(NK - 1) & 1]);

  // epilogue: silu(g)*u -> bf16. C/D layout: col=lane&15, row=(lane>>4)*4+reg
#pragma unroll
  for (int mf = 0; mf < 4; ++mf)
#pragma unroll
    for (int nf = 0; nf < 2; ++nf)
#pragma unroll
      for (int r = 0; r < 4; ++r) {
        float gv = accg[mf][nf][r];
        float uv = accu[mf][nf][r];
        float h  = (gv / (1.f + __expf(-gv))) * uv;
        int c = mf * 16 + (lane >> 4) * 4 + r;
        int f = n0 + wv * 32 + nf * 16 + rl;
        H[((size_t)(e * C) + c) * DF + f] = f2bf(h);
      }
}

// ---------------- Stage 2: out = H * Wd^T (fp32 out) -----------------------
__global__ __launch_bounds__(256, 4) void ffn_stage2(
    const u16* __restrict__ H, const float* __restrict__ Wd,
    float* __restrict__ out) {
  const int b   = blockIdx.x;          // 0..511
  const int xcd = b & 7;
  const int j   = b >> 3;
  const int e   = xcd + 8 * (j >> 3);  // same XCD that produced H[e]
  const int n0  = (j & 7) * BN;

  const int tid  = threadIdx.x;
  const int lane = tid & 63;
  const int wv   = tid >> 6;
  const int rl   = lane & 15;
  const int q    = lane >> 4;

  // per buffer: H 4KB | Wd 16KB = 20KB; x2 = 40KB -> 4 blocks/CU
  __shared__ __align__(16) char lds[2][20480];
  constexpr int OH = 0, OW = 4096;

  const u16*   hbase = H  + (size_t)(e * C) * DF;
  const float* wbase = Wd + ((size_t)e * D + n0) * DF;

  // one K-tile: exactly 5 global_load_lds per wave
  auto STAGE = [&](char* lb, int kt) {
    {  // H: 64 rows x 64B (32 bf16), swz granule ^ ((row>>1)&3)
      const int row = tid >> 2;
      const int gc  = (tid & 3) ^ ((row >> 1) & 3);
      gl_lds16(hbase + (size_t)row * DF + (size_t)kt * BK + gc * 8, lb + OH + tid * 16);
    }
#pragma unroll
    for (int i = 0; i < 4; ++i) {  // Wd: 128 rows x 128B
      const int o   = tid + i * 256;
      const int row = o >> 3;
      const int gc  = (o & 7) ^ (row & 7);
      gl_lds16(wbase + (size_t)row * DF + (size_t)kt * BK + gc * 4, lb + OW + o * 16);
    }
  };

  const f32x4 zero = {0.f, 0.f, 0.f, 0.f};
  f32x4 acc[4][2];
#pragma unroll
  for (int mf = 0; mf < 4; ++mf)
#pragma unroll
    for (int nf = 0; nf < 2; ++nf) acc[mf][nf] = zero;

  auto COMPUTE = [&](const char* lb) {
    short8 a[4], bfr[2];
#pragma unroll
    for (int mf = 0; mf < 4; ++mf) {  // bf16 H frags, swizzled read
      const int r  = mf * 16 + rl;
      const int gp = q ^ ((r >> 1) & 3);
      a[mf] = *reinterpret_cast<const short8*>(lb + OH + r * 64 + gp * 16);
    }
#pragma unroll
    for (int nf = 0; nf < 2; ++nf)
      bfr[nf] = rd_frag_f32(lb + OW, wv * 32 + nf * 16 + rl, q);
#pragma unroll
    for (int mf = 0; mf < 4; ++mf)
#pragma unroll
      for (int nf = 0; nf < 2; ++nf)
        acc[mf][nf] = __builtin_amdgcn_mfma_f32_16x16x32_bf16(a[mf], bfr[nf], acc[mf][nf], 0, 0, 0);
  };

  constexpr int NK = DF / BK;  // 64
  STAGE(lds[0], 0);
  STAGE(lds[1], 1);            // 10 outstanding

  for (int kt = 0; kt < NK - 1; ++kt) {
    asm volatile("s_waitcnt vmcnt(5)" ::: "memory");
    __builtin_amdgcn_s_barrier();
    __builtin_amdgcn_sched_barrier(0);
    COMPUTE(lds[kt & 1]);
    __builtin_amdgcn_sched_barrier(0);
    __builtin_amdgcn_s_barrier();
    if (kt + 2 < NK) STAGE(lds[kt & 1], kt + 2);
  }
  asm volatile("s_waitcnt vmcnt(0)" ::: "memory");
  __builtin_amdgcn_s_barrier();
  __builtin_amdgcn_sched_barrier(0);
  COMPUTE(lds[(NK - 1) & 1]);

#pragma unroll
  for (int mf = 0; mf < 4; ++mf)
#pragma unroll
    for (int nf = 0; nf < 2; ++nf)
#pragma unroll
      for (int r = 0; r < 4; ++r) {
        int c = mf * 16 + (lane >> 4) * 4 + r;
        int d = n0 + wv * 32 + nf * 16 + rl;
        out[((size_t)(e * C) + c) * D + d] = acc[mf][nf][r];
      }
}

}  // namespace

extern "C" void kernel_launch(void* const* d_in, const int* in_sizes, int n_in,
                              void* d_out, int out_size, void* d_ws, size_t ws_size,
                              hipStream_t stream) {
  const float* X  = (const float*)d_in[0];
  const float* Wg = (const float*)d_in[1];
  const float* Wu = (const float*)d_in[2];
  const float* Wd = (const float*)d_in[3];
  float* out = (float*)d_out;
  u16* H = (u16*)d_ws;  // E*C*DF bf16 = 16.8 MB scratch

  ffn_stage1<<<dim3(E * (DF / BN)), dim3(256), 0, stream>>>(X, Wg, Wu, H);
  ffn_stage2<<<dim3(E * (D / BN)), dim3(256), 0, stream>>>(H, Wd, out);
}